// Round 7
// baseline (527.255 us; speedup 1.0000x reference)
//
#include <hip/hip_runtime.h>
#include <hip/hip_bf16.h>

typedef unsigned short u16;
typedef __attribute__((ext_vector_type(8))) short bf16x8;
typedef __attribute__((ext_vector_type(4))) float f32x4;
typedef __attribute__((ext_vector_type(8))) unsigned short ushort8;

#define FEAT 1024
#define NOUT 16384
#define EPS 1e-6f
#define NT 16            // K-tiles of 64

#define GLOBAL_AS __attribute__((address_space(1)))
#define LDS_AS __attribute__((address_space(3)))

__device__ __forceinline__ void load16_to_lds(const u16* g, u16* l) {
    __builtin_amdgcn_global_load_lds((const GLOBAL_AS void*)g, (LDS_AS void*)l, 16, 0, 0);
}

__device__ __forceinline__ u16 f32_to_bf16_bits(float f) {
    __hip_bfloat16 h = __float2bfloat16(f);
    return *reinterpret_cast<u16*>(&h);
}

__device__ __forceinline__ float bf16_bits_to_f32(u16 b) {
    unsigned u = ((unsigned)b) << 16;
    float f;
    __builtin_memcpy(&f, &u, 4);
    return f;
}

// Build Wb with a baked-in within-64-row permutation:
//   Wb[p] = W_row[ (p & ~63) | ((p&15)<<2) | ((p>>4)&3) ]
// so the 16x16-MFMA epilogue fragment (nj, fr) maps to 4 CONTIGUOUS output
// columns fr*4+nj (coalesced 8B packed stores).
__global__ void wbuild_kernel(const float* __restrict__ w, u16* __restrict__ Wb) {
    const int t  = blockIdx.x * 256 + threadIdx.x;
    const int p  = t >> 7;                      // Wb row (permuted position)
    const int k0 = (t & 127) << 3;
    const int o  = (p & ~63) | ((p & 15) << 2) | ((p >> 4) & 3);  // logical W row
    const int ai = o >> 9;
    const int bi = (o >> 4) & 31;
    const int ci = o & 15;
    const float* A = w + ai * FEAT + k0;
    const float* B = w + (32 + bi) * FEAT + k0;
    const float* C = w + (64 + ci) * FEAT + k0;
    ushort8 r;
#pragma unroll
    for (int j = 0; j < 8; ++j) r[j] = f32_to_bf16_bits(A[j] * B[j] * C[j]);
    *reinterpret_cast<ushort8*>(Wb + (size_t)t * 8) = r;
}

__global__ void xcast_kernel(const float* __restrict__ x, u16* __restrict__ Xb) {
    const int t = blockIdx.x * 256 + threadIdx.x;
    const float4* xv = reinterpret_cast<const float4*>(x) + (size_t)t * 2;
    const float4 f0 = xv[0];
    const float4 f1 = xv[1];
    float vals[8] = {f0.x, f0.y, f0.z, f0.w, f1.x, f1.y, f1.z, f1.w};
    ushort8 r;
#pragma unroll
    for (int j = 0; j < 8; ++j) r[j] = f32_to_bf16_bits(vals[j]);
    *reinterpret_cast<ushort8*>(Xb + (size_t)t * 8) = r;
}

// -------- 256x256 GEMM: A via LDS (XOR-swizzled), B direct global->regs ----
// 512 threads = 8 waves (2 M-halves x 4 N-quarters), wave tile 128x64.
// LDS: 2 buffers x (A 256x64) bf16 = 64 KiB, [buf][khalf][256 rows][32 cols].
// Per tile t (buf = t&1):
//  h0: LD_B(t,k1)->bOdd; STAGE A(t+1)->nbuf (t in [1,NT-2]); MFMA k0 (bEven)
//  h1: LD_B(t+1,k0)->bEven; MFMA k1 (bOdd); vmcnt(4) publishes A(t+1); barrier
// B regs double-buffer: compiler emits exact counted vmcnt for B use (B
// issued BEFORE stage in program order, pinned by sched_barrier, so the
// B-wait leaves the 4 stage loads in flight). One barrier per K-tile: WAR on
// nbuf is sealed by tile t-1's end barrier (reads complete before a wave
// passes its MFMA issue, hence before the barrier).

#define LOFF(buf, kh) ((buf) * 16384 + (kh) * 8192)   // u16 units

#define STAGE_A(tt, buf) do {                                                 \
    const u16* g = gA + (size_t)(tt) * 64 + (size_t)w * 32768;                \
    u16* l0 = lds + LOFF(buf, 0) + w * 1024;                                  \
    u16* l1 = lds + LOFF(buf, 1) + w * 1024;                                  \
    load16_to_lds(g,             l0);                                         \
    load16_to_lds(g + 16384,     l0 + 512);                                   \
    load16_to_lds(g + 32,        l1);                                         \
    load16_to_lds(g + 32 + 16384, l1 + 512);                                  \
} while (0)

#define LD_B(dst, tt, kh) do {                                                \
    const u16* gb = gB + (size_t)(tt) * 64 + (kh) * 32;                       \
    dst[0] = *reinterpret_cast<const bf16x8*>(gb);                            \
    dst[1] = *reinterpret_cast<const bf16x8*>(gb + 16 * FEAT);                \
    dst[2] = *reinterpret_cast<const bf16x8*>(gb + 32 * FEAT);                \
    dst[3] = *reinterpret_cast<const bf16x8*>(gb + 48 * FEAT);                \
} while (0)

#define RD_A(dst, mi, mh, kh, buf) dst = *reinterpret_cast<const bf16x8*>(    \
    lds + LOFF(buf, kh) + (wm * 128 + (mh) * 64 + (mi) * 16 + fr) * 32 +      \
    ((kg ^ ((fr >> 1) & 3)) << 3))

#define BAR() do {                                                            \
    __builtin_amdgcn_sched_barrier(0);                                        \
    __builtin_amdgcn_s_barrier();                                             \
    __builtin_amdgcn_sched_barrier(0);                                        \
} while (0)

#define MFMAQ(mh, kh, buf, bb) do {                                           \
    bf16x8 a0, a1, a2, a3;                                                    \
    RD_A(a0, 0, mh, kh, buf); RD_A(a1, 1, mh, kh, buf);                       \
    RD_A(a2, 2, mh, kh, buf); RD_A(a3, 3, mh, kh, buf);                       \
    __builtin_amdgcn_s_setprio(1);                                            \
    acc[(mh)*4+0][0] = __builtin_amdgcn_mfma_f32_16x16x32_bf16(a0, bb[0], acc[(mh)*4+0][0], 0, 0, 0); \
    acc[(mh)*4+0][1] = __builtin_amdgcn_mfma_f32_16x16x32_bf16(a0, bb[1], acc[(mh)*4+0][1], 0, 0, 0); \
    acc[(mh)*4+0][2] = __builtin_amdgcn_mfma_f32_16x16x32_bf16(a0, bb[2], acc[(mh)*4+0][2], 0, 0, 0); \
    acc[(mh)*4+0][3] = __builtin_amdgcn_mfma_f32_16x16x32_bf16(a0, bb[3], acc[(mh)*4+0][3], 0, 0, 0); \
    acc[(mh)*4+1][0] = __builtin_amdgcn_mfma_f32_16x16x32_bf16(a1, bb[0], acc[(mh)*4+1][0], 0, 0, 0); \
    acc[(mh)*4+1][1] = __builtin_amdgcn_mfma_f32_16x16x32_bf16(a1, bb[1], acc[(mh)*4+1][1], 0, 0, 0); \
    acc[(mh)*4+1][2] = __builtin_amdgcn_mfma_f32_16x16x32_bf16(a1, bb[2], acc[(mh)*4+1][2], 0, 0, 0); \
    acc[(mh)*4+1][3] = __builtin_amdgcn_mfma_f32_16x16x32_bf16(a1, bb[3], acc[(mh)*4+1][3], 0, 0, 0); \
    acc[(mh)*4+2][0] = __builtin_amdgcn_mfma_f32_16x16x32_bf16(a2, bb[0], acc[(mh)*4+2][0], 0, 0, 0); \
    acc[(mh)*4+2][1] = __builtin_amdgcn_mfma_f32_16x16x32_bf16(a2, bb[1], acc[(mh)*4+2][1], 0, 0, 0); \
    acc[(mh)*4+2][2] = __builtin_amdgcn_mfma_f32_16x16x32_bf16(a2, bb[2], acc[(mh)*4+2][2], 0, 0, 0); \
    acc[(mh)*4+2][3] = __builtin_amdgcn_mfma_f32_16x16x32_bf16(a2, bb[3], acc[(mh)*4+2][3], 0, 0, 0); \
    acc[(mh)*4+3][0] = __builtin_amdgcn_mfma_f32_16x16x32_bf16(a3, bb[0], acc[(mh)*4+3][0], 0, 0, 0); \
    acc[(mh)*4+3][1] = __builtin_amdgcn_mfma_f32_16x16x32_bf16(a3, bb[1], acc[(mh)*4+3][1], 0, 0, 0); \
    acc[(mh)*4+3][2] = __builtin_amdgcn_mfma_f32_16x16x32_bf16(a3, bb[2], acc[(mh)*4+3][2], 0, 0, 0); \
    acc[(mh)*4+3][3] = __builtin_amdgcn_mfma_f32_16x16x32_bf16(a3, bb[3], acc[(mh)*4+3][3], 0, 0, 0); \
    __builtin_amdgcn_s_setprio(0);                                            \
} while (0)

#define TILE(t, buf, nbuf) do {                                               \
    LD_B(bOdd, t, 1);                                                         \
    __builtin_amdgcn_sched_barrier(0);                                        \
    if ((t) >= 1 && (t) < NT - 1) STAGE_A((t) + 1, nbuf);                     \
    __builtin_amdgcn_sched_barrier(0);                                        \
    MFMAQ(0, 0, buf, bEven);                                                  \
    MFMAQ(1, 0, buf, bEven);                                                  \
    if ((t) < NT - 1) LD_B(bEven, (t) + 1, 0);                                \
    __builtin_amdgcn_sched_barrier(0);                                        \
    MFMAQ(0, 1, buf, bOdd);                                                   \
    MFMAQ(1, 1, buf, bOdd);                                                   \
    if ((t) < NT - 1) {                                                       \
        asm volatile("s_waitcnt vmcnt(4)" ::: "memory");                      \
        BAR();                                                                \
    }                                                                         \
} while (0)

__global__ __launch_bounds__(512, 2) void gemm_kernel(const u16* __restrict__ Xb,
                                                      const u16* __restrict__ Wb,
                                                      u16* __restrict__ Y) {
    __shared__ u16 lds[32768];   // 64 KiB: 2 x (256x64 bf16 A-tile)

    const int tid  = threadIdx.x;
    const int lane = tid & 63;
    const int w    = tid >> 6;     // wave 0..7
    const int wm   = w >> 2;       // M-half
    const int wn   = w & 3;        // N-quarter
    const int fr   = lane & 15;
    const int kg   = lane >> 4;

    // XCD-aware 2D mapping: xcd = bid%8 owns col-blocks [xcd*8, xcd*8+8),
    // walks rows with 4-col inner chunks (W panel L2-resident).
    const int bid = blockIdx.x;            // 0..2047
    const int xcd = bid & 7;
    const int o   = bid >> 3;              // 0..255
    const int cb  = xcd * 8 + (o >> 7) * 4 + (o & 3);  // 0..63
    const int rb  = (o >> 2) & 31;                     // 0..31
    const int brow = rb * 256;
    const int bcol = cb * 256;

    // A staging source (pre-swizzled global, linear LDS dest)
    const int srow   = lane >> 2;                       // 0..15
    const int kchunk = (lane & 3) ^ ((lane >> 3) & 3);  // phys->logical swizzle
    const u16* gA = Xb + (size_t)(brow + srow) * FEAT + kchunk * 8;
    // B fragment source: lane (fr,kg) reads Wb row (bcol+wn*64+n*16+fr), k kg*8
    const u16* gB = Wb + (size_t)(bcol + wn * 64 + fr) * FEAT + kg * 8;

    f32x4 acc[8][4] = {};
    bf16x8 bEven[4], bOdd[4];

    // prologue: A tiles 0,1 staged; B(0,k0) loaded.
    STAGE_A(0, 0);
    STAGE_A(1, 1);
    LD_B(bEven, 0, 0);
    asm volatile("s_waitcnt vmcnt(8)" ::: "memory");   // A(0)'s 4 loads done
    BAR();

    for (int tt = 0; tt < NT; tt += 2) {
        TILE(tt, 0, 1);
        TILE(tt + 1, 1, 0);
    }

    // ------------- epilogue: packed coalesced bf16 stores -------------
    // fragment (nj, fr) = output col bcol + wn*64 + fr*4 + nj (perm in wbuild)
    const int colbase = bcol + wn * 64 + fr * 4;
#pragma unroll
    for (int mi = 0; mi < 8; ++mi) {
#pragma unroll
        for (int r = 0; r < 4; ++r) {
            const int row = brow + wm * 128 + mi * 16 + kg * 4 + r;
            const unsigned lo = (unsigned)f32_to_bf16_bits(acc[mi][0][r]) |
                                ((unsigned)f32_to_bf16_bits(acc[mi][1][r]) << 16);
            const unsigned hi = (unsigned)f32_to_bf16_bits(acc[mi][2][r]) |
                                ((unsigned)f32_to_bf16_bits(acc[mi][3][r]) << 16);
            uint2 pk; pk.x = lo; pk.y = hi;
            *reinterpret_cast<uint2*>(Y + (size_t)row * 32768 + colbase) = pk;
        }
    }
}

// Per-row scale: read bf16 y row, compute sum-of-squares from it, write fp32
// normalized row in-place over the same 64KB row slot.
__global__ __launch_bounds__(1024) void scale_kernel(const u16* __restrict__ Y,
                                                     float* __restrict__ out) {
    const int row = blockIdx.x;
    const int tid = threadIdx.x;
    const ushort8* yr = reinterpret_cast<const ushort8*>(Y + (size_t)row * 32768);
    const ushort8 v0 = yr[2 * tid];
    const ushort8 v1 = yr[2 * tid + 1];

    float f[16];
#pragma unroll
    for (int j = 0; j < 8; ++j) {
        f[j]     = bf16_bits_to_f32(v0[j]);
        f[8 + j] = bf16_bits_to_f32(v1[j]);
    }
    float ss = 0.f;
#pragma unroll
    for (int j = 0; j < 16; ++j) ss += f[j] * f[j];

#pragma unroll
    for (int off = 1; off < 64; off <<= 1) ss += __shfl_xor(ss, off, 64);
    __shared__ float wss[16];
    if ((tid & 63) == 0) wss[tid >> 6] = ss;
    __syncthreads();
    float tot = 0.f;
#pragma unroll
    for (int i = 0; i < 16; ++i) tot += wss[i];
    const float sc = rsqrtf(tot * (1.0f / (float)NOUT) + EPS);

    float4* orow = reinterpret_cast<float4*>(out + (size_t)row * NOUT) + tid * 4;
#pragma unroll
    for (int q = 0; q < 4; ++q) {
        float4 ov;
        ov.x = f[q * 4 + 0] * sc;
        ov.y = f[q * 4 + 1] * sc;
        ov.z = f[q * 4 + 2] * sc;
        ov.w = f[q * 4 + 3] * sc;
        orow[q] = ov;
    }
}

extern "C" void kernel_launch(void* const* d_in, const int* in_sizes, int n_in,
                              void* d_out, int out_size, void* d_ws, size_t ws_size,
                              hipStream_t stream) {
    const float* x = (const float*)d_in[0];   // (8192,1024) fp32
    const float* w = (const float*)d_in[1];   // (80,1024) fp32
    float* out = (float*)d_out;               // (8192,16384) fp32

    const int M = in_sizes[0] / FEAT;         // 8192

    u16* Wb = (u16*)d_ws;                                      // 32 MiB
    u16* Xb = (u16*)((char*)d_ws + (size_t)NOUT * FEAT * 2);   // 16 MiB

    u16* Y = (u16*)d_out;   // bf16 y in first 32KB of each 64KB out row

    wbuild_kernel<<<(NOUT * (FEAT / 8)) / 256, 256, 0, stream>>>(w, Wb);
    xcast_kernel<<<(M * FEAT / 8) / 256, 256, 0, stream>>>(x, Xb);

    const int nblk = (M / 256) * (NOUT / 256);   // 2048
    gemm_kernel<<<nblk, 512, 0, stream>>>(Xb, Wb, Y);

    scale_kernel<<<M, 1024, 0, stream>>>(Y, out);
}

// Round 8
// 466.867 us; speedup vs baseline: 1.1293x; 1.1293x over previous
//
#include <hip/hip_runtime.h>
#include <hip/hip_bf16.h>

typedef unsigned short u16;
typedef __attribute__((ext_vector_type(8))) short bf16x8;
typedef __attribute__((ext_vector_type(4))) float f32x4;
typedef __attribute__((ext_vector_type(8))) unsigned short ushort8;

#define FEAT 1024
#define NOUT 16384
#define EPS 1e-6f
#define NT 32            // K-tiles of 32

#define GLOBAL_AS __attribute__((address_space(1)))
#define LDS_AS __attribute__((address_space(3)))

__device__ __forceinline__ void load16_to_lds(const u16* g, u16* l) {
    __builtin_amdgcn_global_load_lds((const GLOBAL_AS void*)g, (LDS_AS void*)l, 16, 0, 0);
}

__device__ __forceinline__ u16 f32_to_bf16_bits(float f) {
    __hip_bfloat16 h = __float2bfloat16(f);
    return *reinterpret_cast<u16*>(&h);
}

__device__ __forceinline__ float bf16_bits_to_f32(u16 b) {
    unsigned u = ((unsigned)b) << 16;
    float f;
    __builtin_memcpy(&f, &u, 4);
    return f;
}

// Build Wb with a baked-in within-64-row permutation:
//   Wb[p] = W_row[ (p & ~63) | ((p&15)<<2) | ((p>>4)&3) ]
// so the 16x16-MFMA epilogue fragment (nj, fr) maps to 4 CONTIGUOUS output
// columns fr*4+nj (coalesced 8B packed stores).
__global__ void wbuild_kernel(const float* __restrict__ w, u16* __restrict__ Wb) {
    const int t  = blockIdx.x * 256 + threadIdx.x;
    const int p  = t >> 7;                      // Wb row (permuted position)
    const int k0 = (t & 127) << 3;
    const int o  = (p & ~63) | ((p & 15) << 2) | ((p >> 4) & 3);  // logical W row
    const int ai = o >> 9;
    const int bi = (o >> 4) & 31;
    const int ci = o & 15;
    const float* A = w + ai * FEAT + k0;
    const float* B = w + (32 + bi) * FEAT + k0;
    const float* C = w + (64 + ci) * FEAT + k0;
    ushort8 r;
#pragma unroll
    for (int j = 0; j < 8; ++j) r[j] = f32_to_bf16_bits(A[j] * B[j] * C[j]);
    *reinterpret_cast<ushort8*>(Wb + (size_t)t * 8) = r;
}

__global__ void xcast_kernel(const float* __restrict__ x, u16* __restrict__ Xb) {
    const int t = blockIdx.x * 256 + threadIdx.x;
    const float4* xv = reinterpret_cast<const float4*>(x) + (size_t)t * 2;
    const float4 f0 = xv[0];
    const float4 f1 = xv[1];
    float vals[8] = {f0.x, f0.y, f0.z, f0.w, f1.x, f1.y, f1.z, f1.w};
    ushort8 r;
#pragma unroll
    for (int j = 0; j < 8; ++j) r[j] = f32_to_bf16_bits(vals[j]);
    *reinterpret_cast<ushort8*>(Xb + (size_t)t * 8) = r;
}

// ------- 256x128 GEMM, BK=32, 2 blocks/CU (4 waves/SIMD occupancy) -------
// 512 threads = 8 waves (4 M x 2 N), wave tile 64x64: acc[4][4] f32x4 =
// 64 AGPR; target total regs <= 128/wave so TWO blocks co-schedule per CU
// (LDS 48 KiB each). Cross-block wave pool hides ds_read latency, barrier
// skew and stage issue under the other block's MFMAs (m114 mechanism).
// LDS: 2 buffers x (A 256x32 + B 128x32) bf16 = 48 KiB, 64B rows,
// 16B chunks XOR-swizzled via pre-swizzled global source.
// Per K-tile t (buf = t&1):
//   [8 ds_read: A mi0-3, B nj0-3] [16 MFMA @prio1] [BAR1 seals reads]
//   [stage t+2 -> buf: A 2 loads + B 1 load] [vmcnt(3) publishes t+1] [BAR2]
// Ledger: outstanding at vmcnt = {t+1: 3 loads, t+2: 3 loads}; vmcnt(3)
// retires exactly t+1's. WAR: stage t+2 overwrites tile-t regions, whose
// reads all completed before their waves passed BAR1. Tail: t==NT-2 ->
// vmcnt(0); t==NT-1 -> no stage/wait/barriers.

#define LA(buf) (lds + (buf) * 12288)
#define LB(buf) (lds + (buf) * 12288 + 8192)

#define STAGE(tt, buf) do {                                                   \
    const int ko = (tt) * 32;                                                 \
    load16_to_lds(gA0 + ko, LA(buf) + w * 512);                               \
    load16_to_lds(gA1 + ko, LA(buf) + 4096 + w * 512);                        \
    load16_to_lds(gB0 + ko, LB(buf) + w * 512);                               \
} while (0)

#define RD_A(dst, mi, buf) dst = *reinterpret_cast<const bf16x8*>(            \
    LA(buf) + (wm * 64 + (mi) * 16 + fr) * 32 + ((kg ^ ((fr >> 1) & 3)) << 3))
#define RD_B(dst, nj, buf) dst = *reinterpret_cast<const bf16x8*>(            \
    LB(buf) + (wn * 64 + (nj) * 16 + fr) * 32 + ((kg ^ ((fr >> 1) & 3)) << 3))

#define BAR() do {                                                            \
    __builtin_amdgcn_sched_barrier(0);                                        \
    __builtin_amdgcn_s_barrier();                                             \
    __builtin_amdgcn_sched_barrier(0);                                        \
} while (0)

#define TILE(t, buf) do {                                                     \
    bf16x8 a0, a1, a2, a3, b0, b1, b2, b3;                                    \
    RD_A(a0, 0, buf); RD_A(a1, 1, buf); RD_A(a2, 2, buf); RD_A(a3, 3, buf);   \
    RD_B(b0, 0, buf); RD_B(b1, 1, buf); RD_B(b2, 2, buf); RD_B(b3, 3, buf);   \
    __builtin_amdgcn_s_setprio(1);                                            \
    acc[0][0] = __builtin_amdgcn_mfma_f32_16x16x32_bf16(a0, b0, acc[0][0], 0, 0, 0); \
    acc[0][1] = __builtin_amdgcn_mfma_f32_16x16x32_bf16(a0, b1, acc[0][1], 0, 0, 0); \
    acc[0][2] = __builtin_amdgcn_mfma_f32_16x16x32_bf16(a0, b2, acc[0][2], 0, 0, 0); \
    acc[0][3] = __builtin_amdgcn_mfma_f32_16x16x32_bf16(a0, b3, acc[0][3], 0, 0, 0); \
    acc[1][0] = __builtin_amdgcn_mfma_f32_16x16x32_bf16(a1, b0, acc[1][0], 0, 0, 0); \
    acc[1][1] = __builtin_amdgcn_mfma_f32_16x16x32_bf16(a1, b1, acc[1][1], 0, 0, 0); \
    acc[1][2] = __builtin_amdgcn_mfma_f32_16x16x32_bf16(a1, b2, acc[1][2], 0, 0, 0); \
    acc[1][3] = __builtin_amdgcn_mfma_f32_16x16x32_bf16(a1, b3, acc[1][3], 0, 0, 0); \
    acc[2][0] = __builtin_amdgcn_mfma_f32_16x16x32_bf16(a2, b0, acc[2][0], 0, 0, 0); \
    acc[2][1] = __builtin_amdgcn_mfma_f32_16x16x32_bf16(a2, b1, acc[2][1], 0, 0, 0); \
    acc[2][2] = __builtin_amdgcn_mfma_f32_16x16x32_bf16(a2, b2, acc[2][2], 0, 0, 0); \
    acc[2][3] = __builtin_amdgcn_mfma_f32_16x16x32_bf16(a2, b3, acc[2][3], 0, 0, 0); \
    acc[3][0] = __builtin_amdgcn_mfma_f32_16x16x32_bf16(a3, b0, acc[3][0], 0, 0, 0); \
    acc[3][1] = __builtin_amdgcn_mfma_f32_16x16x32_bf16(a3, b1, acc[3][1], 0, 0, 0); \
    acc[3][2] = __builtin_amdgcn_mfma_f32_16x16x32_bf16(a3, b2, acc[3][2], 0, 0, 0); \
    acc[3][3] = __builtin_amdgcn_mfma_f32_16x16x32_bf16(a3, b3, acc[3][3], 0, 0, 0); \
    __builtin_amdgcn_s_setprio(0);                                            \
    if ((t) < NT - 1) {                                                       \
        BAR();                                                                \
        if ((t) < NT - 2) {                                                   \
            STAGE((t) + 2, buf);                                              \
            asm volatile("s_waitcnt vmcnt(3)" ::: "memory");                  \
        } else {                                                              \
            asm volatile("s_waitcnt vmcnt(0)" ::: "memory");                  \
        }                                                                     \
        BAR();                                                                \
    }                                                                         \
} while (0)

__global__ __launch_bounds__(512, 4) void gemm_kernel(const u16* __restrict__ Xb,
                                                      const u16* __restrict__ Wb,
                                                      u16* __restrict__ Y) {
    __shared__ u16 lds[24576];   // 48 KiB

    const int tid  = threadIdx.x;
    const int lane = tid & 63;
    const int w    = tid >> 6;     // wave 0..7
    const int wm   = w >> 1;       // M quarter (0..3)
    const int wn   = w & 1;        // N half (0..1)
    const int fr   = lane & 15;
    const int kg   = lane >> 4;

    // XCD-aware mapping: xcd owns 16 col-blocks (W panel 4MB, L2-resident),
    // walks rows with 4-col inner chunks.
    const int bid = blockIdx.x;            // 0..4095
    const int xcd = bid & 7;
    const int o   = bid >> 3;              // 0..511
    const int cb  = xcd * 16 + (o >> 7) * 4 + (o & 3);  // 0..127
    const int rb  = (o >> 2) & 31;                      // 0..31
    const int brow = rb * 256;
    const int bcol = cb * 128;

    // staging sources (pre-swizzled global, linear LDS dest)
    const int srow = tid >> 2;                        // 0..127
    const int kc   = (tid & 3) ^ ((srow >> 1) & 3);   // phys->logical swizzle
    const u16* gA0 = Xb + (size_t)(brow + srow) * FEAT + kc * 8;         // rows 0..127
    const u16* gA1 = gA0 + 128 * FEAT;                                    // rows 128..255
    const u16* gB0 = Wb + (size_t)(bcol + srow) * FEAT + kc * 8;         // rows 0..127

    f32x4 acc[4][4] = {};

    // prologue: tiles 0 (buf0) and 1 (buf1); vmcnt(3) retires tile 0's 3.
    STAGE(0, 0);
    STAGE(1, 1);
    asm volatile("s_waitcnt vmcnt(3)" ::: "memory");
    BAR();

#pragma unroll 2
    for (int tt = 0; tt < NT; ++tt) {
        TILE(tt, (tt & 1));
    }

    // ------------- epilogue: packed coalesced bf16 stores -------------
    // fragment (nj, fr) = output col bcol + wn*64 + fr*4 + nj (perm in wbuild)
    const int colbase = bcol + wn * 64 + fr * 4;
#pragma unroll
    for (int mi = 0; mi < 4; ++mi) {
#pragma unroll
        for (int r = 0; r < 4; ++r) {
            const int row = brow + wm * 64 + mi * 16 + kg * 4 + r;
            const unsigned lo = (unsigned)f32_to_bf16_bits(acc[mi][0][r]) |
                                ((unsigned)f32_to_bf16_bits(acc[mi][1][r]) << 16);
            const unsigned hi = (unsigned)f32_to_bf16_bits(acc[mi][2][r]) |
                                ((unsigned)f32_to_bf16_bits(acc[mi][3][r]) << 16);
            uint2 pk; pk.x = lo; pk.y = hi;
            *reinterpret_cast<uint2*>(Y + (size_t)row * 32768 + colbase) = pk;
        }
    }
}

// Per-row scale: read bf16 y row, compute sum-of-squares from it, write fp32
// normalized row in-place over the same 64KB row slot.
__global__ __launch_bounds__(1024) void scale_kernel(const u16* __restrict__ Y,
                                                     float* __restrict__ out) {
    const int row = blockIdx.x;
    const int tid = threadIdx.x;
    const ushort8* yr = reinterpret_cast<const ushort8*>(Y + (size_t)row * 32768);
    const ushort8 v0 = yr[2 * tid];
    const ushort8 v1 = yr[2 * tid + 1];

    float f[16];
#pragma unroll
    for (int j = 0; j < 8; ++j) {
        f[j]     = bf16_bits_to_f32(v0[j]);
        f[8 + j] = bf16_bits_to_f32(v1[j]);
    }
    float ss = 0.f;
#pragma unroll
    for (int j = 0; j < 16; ++j) ss += f[j] * f[j];

#pragma unroll
    for (int off = 1; off < 64; off <<= 1) ss += __shfl_xor(ss, off, 64);
    __shared__ float wss[16];
    if ((tid & 63) == 0) wss[tid >> 6] = ss;
    __syncthreads();
    float tot = 0.f;
#pragma unroll
    for (int i = 0; i < 16; ++i) tot += wss[i];
    const float sc = rsqrtf(tot * (1.0f / (float)NOUT) + EPS);

    float4* orow = reinterpret_cast<float4*>(out + (size_t)row * NOUT) + tid * 4;
#pragma unroll
    for (int q = 0; q < 4; ++q) {
        float4 ov;
        ov.x = f[q * 4 + 0] * sc;
        ov.y = f[q * 4 + 1] * sc;
        ov.z = f[q * 4 + 2] * sc;
        ov.w = f[q * 4 + 3] * sc;
        orow[q] = ov;
    }
}

extern "C" void kernel_launch(void* const* d_in, const int* in_sizes, int n_in,
                              void* d_out, int out_size, void* d_ws, size_t ws_size,
                              hipStream_t stream) {
    const float* x = (const float*)d_in[0];   // (8192,1024) fp32
    const float* w = (const float*)d_in[1];   // (80,1024) fp32
    float* out = (float*)d_out;               // (8192,16384) fp32

    const int M = in_sizes[0] / FEAT;         // 8192

    u16* Wb = (u16*)d_ws;                                      // 32 MiB
    u16* Xb = (u16*)((char*)d_ws + (size_t)NOUT * FEAT * 2);   // 16 MiB

    u16* Y = (u16*)d_out;   // bf16 y in first 32KB of each 64KB out row

    wbuild_kernel<<<(NOUT * (FEAT / 8)) / 256, 256, 0, stream>>>(w, Wb);
    xcast_kernel<<<(M * FEAT / 8) / 256, 256, 0, stream>>>(x, Xb);

    const int nblk = (M / 256) * (NOUT / 128);   // 4096
    gemm_kernel<<<nblk, 512, 0, stream>>>(Xb, Wb, Y);

    scale_kernel<<<M, 1024, 0, stream>>>(Y, out);
}